// Round 5
// baseline (272.409 us; speedup 1.0000x reference)
//
#include <hip/hip_runtime.h>

// Problem constants: B=2, S=2048, D=1024, H=16, DK=64
#define S_LEN 2048
#define DMODEL 1024
#define DHEAD 64

typedef _Float16 half8 __attribute__((ext_vector_type(8)));
typedef _Float16 half4 __attribute__((ext_vector_type(4)));
typedef float f32x4 __attribute__((ext_vector_type(4)));
typedef int i32x4 __attribute__((ext_vector_type(4)));

#define LOG2E 1.4426950408889634f

// async global->LDS, 16B per lane; LDS dest is wave-uniform base, HW writes lane i at base+16*i.
__device__ __forceinline__ void async_copy16(const void* g, void* l) {
  __builtin_amdgcn_global_load_lds((__attribute__((address_space(1))) const void*)g,
                                   (__attribute__((address_space(3))) void*)l,
                                   16, 0, 0);
}

// ---------------- convert wq,wk,wv fp32 -> fp16 ----------------
__global__ __launch_bounds__(256) void convert_w(const float* __restrict__ wq,
                                                 const float* __restrict__ wk,
                                                 const float* __restrict__ wv,
                                                 _Float16* __restrict__ dst) {
  const float* src = (blockIdx.y == 0) ? wq : (blockIdx.y == 1) ? wk : wv;
  _Float16* d = dst + (size_t)blockIdx.y * (DMODEL * DMODEL);
  int i = (blockIdx.x * 256 + threadIdx.x) * 4;
  float4 v = *(const float4*)(src + i);
  half4 h;
  h[0] = (_Float16)v.x; h[1] = (_Float16)v.y;
  h[2] = (_Float16)v.z; h[3] = (_Float16)v.w;
  *(half4*)(d + i) = h;
}

// ---------------- convert wo fp32 -> fp16 (runs after attn; vt slot is dead) ----------------
__global__ __launch_bounds__(256) void convert_wo(const float* __restrict__ wo,
                                                  _Float16* __restrict__ dst) {
  int i = (blockIdx.x * 256 + threadIdx.x) * 4;
  float4 v = *(const float4*)(wo + i);
  half4 h;
  h[0] = (_Float16)v.x; h[1] = (_Float16)v.y;
  h[2] = (_Float16)v.z; h[3] = (_Float16)v.w;
  *(half4*)(dst + i) = h;
}

// ---------------- fused QKV projection GEMM v2: pipelined + swizzled LDS ----------------
// C[m,n] = sum_k A[m,k]*W[n,k] + bias[n]; A fp32 (prefetched to regs, cvt to fp16 on write),
// W fp16 (async DMA with pre-swizzled source). Double-buffered LDS, 1 barrier/K-step:
// tile k+1's B-DMA + A-global-loads issue at the TOP of step k so latency hides under MFMA.
// LDS granule swizzle g' = g ^ ((row>>1)&3) (16B granules, 64B rows): all ds_read_b128 /
// ds_write_b128 hit 8 distinct bank-slots per 8-lane group (conflict-free).
// sel 0:q (scaled 0.125*LOG2E) 1:k 2:v (TRANSPOSED out: vt[b,h,dk,s])
__global__ __launch_bounds__(256) void qkv_gemm(
    const float* __restrict__ Qf, const float* __restrict__ Kf, const float* __restrict__ Vf,
    const _Float16* __restrict__ wh,
    const float* __restrict__ bq, const float* __restrict__ bk, const float* __restrict__ bv,
    _Float16* __restrict__ qo, _Float16* __restrict__ ko, _Float16* __restrict__ vt) {
  __shared__ __align__(16) _Float16 As[2][128 * 32];
  __shared__ __align__(16) _Float16 Bs[2][128 * 32];
  const int tid = threadIdx.x;
  const int wave = tid >> 6, lane = tid & 63;
  const int m15 = lane & 15, quad = lane >> 4;
  const int m0 = blockIdx.x * 128;
  const int gn0 = blockIdx.y * 128;
  const int sel = gn0 >> 10;       // 0:q 1:k 2:v (128 | 1024, no straddle)
  const int n0 = gn0 & 1023;
  const float* Ag = (sel == 0) ? Qf : (sel == 1) ? Kf : Vf;
  const _Float16* Wg = wh + (size_t)sel * (DMODEL * DMODEL);
  const float* bias = (sel == 0) ? bq : (sel == 1) ? bk : bv;

  const int wm = (wave & 1) * 64, wn = (wave >> 1) * 64;
  const int sr = tid >> 1, sc16 = (tid & 1) * 16;  // A staging coords (row, col base)
  const int g0 = (tid & 1) * 2, asw = (sr >> 1) & 3;
  const int rgr = (quad ^ ((m15 >> 1) & 3)) << 4;  // swizzled read-granule byte offset

  f32x4 acc[4][4];
#pragma unroll
  for (int i = 0; i < 4; i++)
#pragma unroll
    for (int j = 0; j < 4; j++) {
      f32x4 z = {0.f, 0.f, 0.f, 0.f};
      acc[i][j] = z;
    }

  const float* ap = Ag + (size_t)(m0 + sr) * DMODEL + sc16;
  float4 f0, f1, f2, f3;

  auto issueB = [&](int kk, int nb) {
#pragma unroll
    for (int p = 0; p < 2; p++) {
      int row = p * 64 + (tid >> 2);
      int gl = (tid & 3) ^ ((row >> 1) & 3);  // pre-swizzled source granule
      async_copy16(Wg + (size_t)(n0 + row) * DMODEL + kk + gl * 8,
                   (char*)&Bs[nb][0] + p * 4096 + wave * 1024);
    }
  };
  auto loadA = [&](int kk) {
    const float* p = ap + kk;
    f0 = ((const float4*)p)[0];
    f1 = ((const float4*)p)[1];
    f2 = ((const float4*)p)[2];
    f3 = ((const float4*)p)[3];
  };
  auto writeA = [&](int nb) {
    half8 h0, h1;
    h0[0] = (_Float16)f0.x; h0[1] = (_Float16)f0.y; h0[2] = (_Float16)f0.z; h0[3] = (_Float16)f0.w;
    h0[4] = (_Float16)f1.x; h0[5] = (_Float16)f1.y; h0[6] = (_Float16)f1.z; h0[7] = (_Float16)f1.w;
    h1[0] = (_Float16)f2.x; h1[1] = (_Float16)f2.y; h1[2] = (_Float16)f2.z; h1[3] = (_Float16)f2.w;
    h1[4] = (_Float16)f3.x; h1[5] = (_Float16)f3.y; h1[6] = (_Float16)f3.z; h1[7] = (_Float16)f3.w;
    char* rb = (char*)&As[nb][0] + sr * 64;
    *(half8*)(rb + ((g0 ^ asw) << 4)) = h0;
    *(half8*)(rb + (((g0 + 1) ^ asw) << 4)) = h1;
  };

  // prologue: tile 0
  issueB(0, 0);
  loadA(0);
  writeA(0);
  __syncthreads();

  for (int kt = 0; kt < 32; kt++) {
    const int buf = kt & 1;
    if (kt < 31) {            // issue tile k+1 early: latency hides under this tile's MFMA
      issueB((kt + 1) * 32, buf ^ 1);
      loadA((kt + 1) * 32);
    }
    half8 af[4], bf[4];
#pragma unroll
    for (int i = 0; i < 4; i++)
      af[i] = *(const half8*)((char*)&As[buf][0] + (wm + i * 16 + m15) * 64 + rgr);
#pragma unroll
    for (int j = 0; j < 4; j++)
      bf[j] = *(const half8*)((char*)&Bs[buf][0] + (wn + j * 16 + m15) * 64 + rgr);
#pragma unroll
    for (int i = 0; i < 4; i++)
#pragma unroll
      for (int j = 0; j < 4; j++)
        acc[i][j] = __builtin_amdgcn_mfma_f32_16x16x32_f16(af[i], bf[j], acc[i][j], 0, 0, 0);
    if (kt < 31) writeA(buf ^ 1);
    __syncthreads();  // drains B-DMA(k+1) (issued ~compute-time ago) + read/write fences
  }
  // epilogue: C/D layout col=lane&15, row=quad*4+r
  if (sel != 2) {
    _Float16* outp = (sel == 0) ? qo : ko;
    const float scale = (sel == 0) ? (0.125f * LOG2E) : 1.0f;
#pragma unroll
    for (int i = 0; i < 4; i++) {
#pragma unroll
      for (int j = 0; j < 4; j++) {
        int gn = n0 + wn + j * 16 + m15;
        float bb = bias[gn];
#pragma unroll
        for (int r = 0; r < 4; r++) {
          int gm = m0 + wm + i * 16 + quad * 4 + r;
          outp[(size_t)gm * DMODEL + gn] = (_Float16)((acc[i][j][r] + bb) * scale);
        }
      }
    }
  } else {
    // V transposed store: vt[((b*16+h)*64+dk)*2048 + s], 4 consecutive s per thread (half4)
#pragma unroll
    for (int i = 0; i < 4; i++) {
      int gm0 = m0 + wm + i * 16 + quad * 4;  // rows r=0..3 contiguous
      int b = gm0 >> 11, s = gm0 & 2047;
#pragma unroll
      for (int j = 0; j < 4; j++) {
        int gn = n0 + wn + j * 16 + m15;
        int h = gn >> 6, dk = gn & 63;
        float bb = bias[gn];
        half4 hv;
        hv[0] = (_Float16)(acc[i][j][0] + bb);
        hv[1] = (_Float16)(acc[i][j][1] + bb);
        hv[2] = (_Float16)(acc[i][j][2] + bb);
        hv[3] = (_Float16)(acc[i][j][3] + bb);
        *(half4*)(vt + ((size_t)(b * 16 + h) * 64 + dk) * 2048 + s) = hv;
      }
    }
  }
}

// ---------------- flash attention v4: hybrid 2x2 wave split, all-b128 LDS, in-reg P ----------------
// (unchanged from round 4 -- verified, no longer the bottleneck)
__global__ __launch_bounds__(256) void attn_kernel(const _Float16* __restrict__ qh,
                                                   const _Float16* __restrict__ kh,
                                                   const _Float16* __restrict__ vt,
                                                   _Float16* __restrict__ ctx) {
  // [0,16K) Ks[2][64][64], [16K,32K) Vs[2][64][64]; epilogue reuses [0,17664) as Ored/Lred.
  __shared__ __align__(16) char smem[32768];
  const int tid = threadIdx.x;
  const int wave = tid >> 6, lane = tid & 63;
  const int m15 = lane & 15, qd = lane >> 4;
  const int wq = wave >> 1, ws = wave & 1;
  const int q0 = blockIdx.x * 64;
  const int h = blockIdx.y, b = blockIdx.z;
  const size_t base = (size_t)b * S_LEN * DMODEL + (size_t)h * DHEAD;  // q/k/ctx base
  const size_t vbase = (size_t)(b * 16 + h) * 64 * 2048;               // vt base

  // Q fragments (pre-scaled by 0.125*log2e): B-layout n=m15 (q row), k=qd*8+j (dk)
  half8 qf[2][2];
#pragma unroll
  for (int qt = 0; qt < 2; qt++) {
    const _Float16* qp = qh + base + (size_t)(q0 + wq * 32 + qt * 16 + m15) * DMODEL + qd * 8;
    qf[qt][0] = *(const half8*)qp;
    qf[qt][1] = *(const half8*)(qp + 32);
  }

  // staging: per-lane pre-swizzled global sources (16B granule: slot s8 holds logical s8^l8)
  const int l8 = lane >> 3, s8 = lane & 7;
  const int swz = (s8 ^ l8) * 8;  // halfs within a 64-half row
  const _Float16* ksrc = kh + base + (size_t)(wave * 8 + l8) * DMODEL + swz;
  const _Float16* vsrc = vt + vbase + (size_t)(wave * 8 + l8) * S_LEN + swz;
  char* kdst = smem + wave * 1024;
  char* vdst = smem + 16384 + wave * 1024;

  // read-side swizzled granule byte offsets (row&7 == m15&7 for all read rows)
  const int kgr = ((qd ^ (m15 & 7)) << 4);             // K: dk granule G=qd (dk 0..31)
  const int vgr = (((ws * 4 + qd) ^ (m15 & 7)) << 4);  // V: s' granule G=ws*4+qd
  const int krow = ws * 32 + m15;                      // + 16t

  f32x4 acc[4][2];  // [dk-tile][q-tile] partial O^T over this wave's 32-s' slice
#pragma unroll
  for (int i = 0; i < 4; i++)
#pragma unroll
    for (int j = 0; j < 2; j++) { f32x4 z = {0.f, 0.f, 0.f, 0.f}; acc[i][j] = z; }
  float ls[2] = {0.f, 0.f};  // per-lane partial row sums (q = qt*16+m15)

  // prologue: stage tile 0 into buf 0
#pragma unroll
  for (int p = 0; p < 2; p++) {
    async_copy16(ksrc + (size_t)(p * 32) * DMODEL, kdst + p * 4096);
    async_copy16(vsrc + (size_t)(p * 32) * S_LEN, vdst + p * 4096);
  }
  __syncthreads();

  for (int it = 0; it < 32; it++) {
    const int buf = it & 1;
    if (it < 31) {
      const int kv = (it + 1) * 64;
#pragma unroll
      for (int p = 0; p < 2; p++) {
        async_copy16(ksrc + (size_t)(kv + p * 32) * DMODEL, kdst + (buf ^ 1) * 8192 + p * 4096);
        async_copy16(vsrc + (size_t)(p * 32) * S_LEN + kv, vdst + (buf ^ 1) * 8192 + p * 4096);
      }
    }
    const char* kb = smem + buf * 8192;
    const char* vb = smem + 16384 + buf * 8192;

    // ---- K slice fragments: A-layout row = ws*32+16t+m15 (s'), k=qd*8+j (dk) ----
    half8 kf[2][2];
#pragma unroll
    for (int t = 0; t < 2; t++) {
      kf[t][0] = *(const half8*)(kb + (krow + 16 * t) * 128 + kgr);
      kf[t][1] = *(const half8*)(kb + (krow + 16 * t) * 128 + (kgr ^ 64));
    }

    // ---- QK^T: sc[t][qt] = P[s'_slice=16t+qd*4+r][q=qt*16+m15] ----
    f32x4 sc[2][2];
#pragma unroll
    for (int t = 0; t < 2; t++)
#pragma unroll
      for (int qt = 0; qt < 2; qt++) {
        f32x4 z = {0.f, 0.f, 0.f, 0.f};
        sc[t][qt] = __builtin_amdgcn_mfma_f32_16x16x32_f16(kf[t][0], qf[qt][0], z, 0, 0, 0);
        sc[t][qt] = __builtin_amdgcn_mfma_f32_16x16x32_f16(kf[t][1], qf[qt][1], sc[t][qt], 0, 0, 0);
      }

    // ---- p = exp2(score) (raw); lane-local row sums; pack pairs to half2 words ----
    int pk[2][2][2];
#pragma unroll
    for (int t = 0; t < 2; t++)
#pragma unroll
      for (int qt = 0; qt < 2; qt++) {
        float e0 = __builtin_amdgcn_exp2f(sc[t][qt][0]);
        float e1 = __builtin_amdgcn_exp2f(sc[t][qt][1]);
        float e2 = __builtin_amdgcn_exp2f(sc[t][qt][2]);
        float e3 = __builtin_amdgcn_exp2f(sc[t][qt][3]);
        ls[qt] += (e0 + e1) + (e2 + e3);
        pk[t][qt][0] = __builtin_bit_cast(int, __builtin_amdgcn_cvt_pkrtz(e0, e1));
        pk[t][qt][1] = __builtin_bit_cast(int, __builtin_amdgcn_cvt_pkrtz(e2, e3));
      }

    // ---- butterfly (validated r2): tiles (0,1) -> lane holds P[s'_slice=qd*8+jj][q],
    // exactly the PV B-fragment (k=qd*8+jj) for the wave's 32-s' slice.
    half8 pA[2];
#pragma unroll
    for (int qt = 0; qt < 2; qt++) {
      i32x4 fh;
#pragma unroll
      for (int p = 0; p < 2; p++) {
        auto s1 = __builtin_amdgcn_permlane32_swap(pk[0][qt][p], pk[1][qt][p], false, false);
        auto s2 = __builtin_amdgcn_permlane16_swap(s1[0], s1[1], false, false);
        fh[p] = (int)s2[0];      // jj 0..3 slot
        fh[2 + p] = (int)s2[1];  // jj 4..7 slot
      }
      pA[qt] = __builtin_bit_cast(half8, fh);
    }

    // ---- PV: acc[td][qt] += V^T[dk=td*16+m15][s' slice] x P (K=32, one b128 per td) ----
#pragma unroll
    for (int td = 0; td < 4; td++) {
      half8 vf = *(const half8*)(vb + (td * 16 + m15) * 128 + vgr);
#pragma unroll
      for (int qt = 0; qt < 2; qt++)
        acc[td][qt] = __builtin_amdgcn_mfma_f32_16x16x32_f16(vf, pA[qt], acc[td][qt], 0, 0, 0);
    }
    __syncthreads();  // drains this wave's DMA (vmcnt 0) + all waves done reading buf
  }

  // ---- cross-ws reduction through LDS (K/V buffers dead after final barrier) ----
  float* Ored = (float*)smem;            // [64 q][68] f32 (stride 68: uniform bank spread)
  float* Lred = (float*)(smem + 17408);  // [64 q] f32 (ws=1 partials)

#pragma unroll
  for (int qt = 0; qt < 2; qt++) {  // reduce over quads (disjoint s' per qd)
    ls[qt] += __shfl_xor(ls[qt], 16);
    ls[qt] += __shfl_xor(ls[qt], 32);
  }

  if (ws == 1) {
#pragma unroll
    for (int qt = 0; qt < 2; qt++) {
      int q = wq * 32 + qt * 16 + m15;
      if (qd == 0) Lred[q] = ls[qt];
#pragma unroll
      for (int td = 0; td < 4; td++)
        *(f32x4*)&Ored[q * 68 + td * 16 + qd * 4] = acc[td][qt];
    }
  }
  __syncthreads();

  if (ws == 0) {
#pragma unroll
    for (int qt = 0; qt < 2; qt++) {
      int q = wq * 32 + qt * 16 + m15;
      const float inv = 1.0f / (ls[qt] + Lred[q]);
#pragma unroll
      for (int td = 0; td < 4; td++) {
        f32x4 o = acc[td][qt] + *(const f32x4*)&Ored[q * 68 + td * 16 + qd * 4];
        half4 hv;
#pragma unroll
        for (int r = 0; r < 4; r++) hv[r] = (_Float16)(o[r] * inv);
        *(half4*)(ctx + base + (size_t)(q0 + q) * DMODEL + td * 16 + qd * 4) = hv;
      }
    }
  }
}

// ---------------- output projection v2: pipelined + swizzled, BM=64 (512 blocks) ----------------
__global__ __launch_bounds__(256) void out_gemm(const _Float16* __restrict__ ch,
                                                const _Float16* __restrict__ who,
                                                const float* __restrict__ bo,
                                                float* __restrict__ out) {
  __shared__ __align__(16) _Float16 As[2][64 * 32];
  __shared__ __align__(16) _Float16 Bs[2][128 * 32];
  const int tid = threadIdx.x;
  const int wave = tid >> 6, lane = tid & 63;
  const int m15 = lane & 15, quad = lane >> 4;
  const int m0 = blockIdx.x * 64, n0 = blockIdx.y * 128;
  const int wm = (wave & 1) * 32, wn = (wave >> 1) * 64;
  const int rgr = (quad ^ ((m15 >> 1) & 3)) << 4;  // swizzled read-granule byte offset

  f32x4 acc[2][4];
#pragma unroll
  for (int i = 0; i < 2; i++)
#pragma unroll
    for (int j = 0; j < 4; j++) {
      f32x4 z = {0.f, 0.f, 0.f, 0.f};
      acc[i][j] = z;
    }

  auto issueAB = [&](int kk, int nb) {
    {  // A tile 64x32: one pass
      int row = tid >> 2;
      int gl = (tid & 3) ^ ((row >> 1) & 3);
      async_copy16(ch + (size_t)(m0 + row) * DMODEL + kk + gl * 8,
                   (char*)&As[nb][0] + wave * 1024);
    }
#pragma unroll
    for (int p = 0; p < 2; p++) {  // B tile 128x32: two passes
      int row = p * 64 + (tid >> 2);
      int gl = (tid & 3) ^ ((row >> 1) & 3);
      async_copy16(who + (size_t)(n0 + row) * DMODEL + kk + gl * 8,
                   (char*)&Bs[nb][0] + p * 4096 + wave * 1024);
    }
  };

  issueAB(0, 0);
  __syncthreads();

  for (int kt = 0; kt < 32; kt++) {
    const int buf = kt & 1;
    if (kt < 31) issueAB((kt + 1) * 32, buf ^ 1);
    half8 af[2], bf[4];
#pragma unroll
    for (int i = 0; i < 2; i++)
      af[i] = *(const half8*)((char*)&As[buf][0] + (wm + i * 16 + m15) * 64 + rgr);
#pragma unroll
    for (int j = 0; j < 4; j++)
      bf[j] = *(const half8*)((char*)&Bs[buf][0] + (wn + j * 16 + m15) * 64 + rgr);
#pragma unroll
    for (int i = 0; i < 2; i++)
#pragma unroll
      for (int j = 0; j < 4; j++)
        acc[i][j] = __builtin_amdgcn_mfma_f32_16x16x32_f16(af[i], bf[j], acc[i][j], 0, 0, 0);
    __syncthreads();
  }
#pragma unroll
  for (int i = 0; i < 2; i++) {
#pragma unroll
    for (int j = 0; j < 4; j++) {
      int gn = n0 + wn + j * 16 + m15;
      float bb = bo[gn];
#pragma unroll
      for (int r = 0; r < 4; r++) {
        int gm = m0 + wm + i * 16 + quad * 4 + r;
        out[(size_t)gm * DMODEL + gn] = acc[i][j][r] + bb;
      }
    }
  }
}

extern "C" void kernel_launch(void* const* d_in, const int* in_sizes, int n_in,
                              void* d_out, int out_size, void* d_ws, size_t ws_size,
                              hipStream_t stream) {
  (void)in_sizes; (void)n_in; (void)out_size; (void)ws_size;
  const float* Q  = (const float*)d_in[0];
  const float* K  = (const float*)d_in[1];
  const float* V  = (const float*)d_in[2];
  const float* wq = (const float*)d_in[3];
  const float* bq = (const float*)d_in[4];
  const float* wk = (const float*)d_in[5];
  const float* bk = (const float*)d_in[6];
  const float* wv = (const float*)d_in[7];
  const float* bv = (const float*)d_in[8];
  const float* wo = (const float*)d_in[9];
  const float* bo = (const float*)d_in[10];
  float* out = (float*)d_out;

  // Scratch plan (16 MB d_ws + d_out reuse), timeline:
  //   qh, kh (fp16, 8 MB each)  -> inside d_out (dead before out_gemm writes fp32 there)
  //   vt (fp16 transposed, 8MB) -> ws[0:8M)   -- alive qkv..attn
  //   wh (fp16 wq|wk|wv, 6 MB)  -> ws[8M:14M) -- alive only during qkv_gemm
  //   ch (fp16 ctx, 8 MB)       -> ws[8M:16M) -- written by attn (overlays wh, disjoint in time)
  //   who (fp16 wo, 2 MB)       -> ws[0:2M)   -- written AFTER attn (overlays dead vt)
  _Float16* qh = (_Float16*)d_out;
  _Float16* kh = qh + (size_t)4194304;
  _Float16* vt = (_Float16*)d_ws;
  _Float16* wh = vt + (size_t)4194304;
  _Float16* ch = vt + (size_t)4194304;
  _Float16* who = (_Float16*)d_ws;

  convert_w<<<dim3(1024, 3), 256, 0, stream>>>(wq, wk, wv, wh);
  qkv_gemm<<<dim3(32, 24), 256, 0, stream>>>(Q, K, V, wh, bq, bk, bv, qh, kh, vt);
  attn_kernel<<<dim3(32, 16, 2), 256, 0, stream>>>(qh, kh, vt, ch);
  convert_wo<<<dim3(1024), 256, 0, stream>>>(wo, who);
  out_gemm<<<dim3(64, 8), 256, 0, stream>>>(ch, who, bo, out);
}

// Round 6
// 236.931 us; speedup vs baseline: 1.1497x; 1.1497x over previous
//
#include <hip/hip_runtime.h>

// Problem constants: B=2, S=2048, D=1024, H=16, DK=64
#define S_LEN 2048
#define DMODEL 1024
#define DHEAD 64

typedef _Float16 half8 __attribute__((ext_vector_type(8)));
typedef _Float16 half4 __attribute__((ext_vector_type(4)));
typedef float f32x4 __attribute__((ext_vector_type(4)));
typedef int i32x4 __attribute__((ext_vector_type(4)));

#define LOG2E 1.4426950408889634f

// async global->LDS, 16B per lane; LDS dest is wave-uniform base, HW writes lane i at base+16*i.
__device__ __forceinline__ void async_copy16(const void* g, void* l) {
  __builtin_amdgcn_global_load_lds((__attribute__((address_space(1))) const void*)g,
                                   (__attribute__((address_space(3))) void*)l,
                                   16, 0, 0);
}

#define WAIT_VMCNT(N) asm volatile("s_waitcnt vmcnt(" #N ")" ::: "memory")
#define RAW_BARRIER() asm volatile("s_barrier" ::: "memory")

// ---------------- convert wq,wk,wv fp32 -> fp16 ----------------
__global__ __launch_bounds__(256) void convert_w(const float* __restrict__ wq,
                                                 const float* __restrict__ wk,
                                                 const float* __restrict__ wv,
                                                 _Float16* __restrict__ dst) {
  const float* src = (blockIdx.y == 0) ? wq : (blockIdx.y == 1) ? wk : wv;
  _Float16* d = dst + (size_t)blockIdx.y * (DMODEL * DMODEL);
  int i = (blockIdx.x * 256 + threadIdx.x) * 4;
  float4 v = *(const float4*)(src + i);
  half4 h;
  h[0] = (_Float16)v.x; h[1] = (_Float16)v.y;
  h[2] = (_Float16)v.z; h[3] = (_Float16)v.w;
  *(half4*)(d + i) = h;
}

// ---------------- convert wo fp32 -> fp16 (runs after attn; vt slot is dead) ----------------
__global__ __launch_bounds__(256) void convert_wo(const float* __restrict__ wo,
                                                  _Float16* __restrict__ dst) {
  int i = (blockIdx.x * 256 + threadIdx.x) * 4;
  float4 v = *(const float4*)(wo + i);
  half4 h;
  h[0] = (_Float16)v.x; h[1] = (_Float16)v.y;
  h[2] = (_Float16)v.z; h[3] = (_Float16)v.w;
  *(half4*)(dst + i) = h;
}

// ---------------- fused QKV projection GEMM v3: counted-vmcnt pipeline ----------------
// C[m,n] = sum_k A[m,k]*W[n,k] + bias[n]. BOTH operands DMA-staged: A as fp32 (16KB/tile,
// cvt fp32->fp16 at fragment load), W fp16. Double-buffered; 2-deep prefetch held in flight
// across RAW s_barriers with counted s_waitcnt vmcnt(6) -- never drained to 0 in the loop
// (the round-5 __syncthreads drain was the latency exposure).
// Swizzles (all verified-conflict-free b128 classes):
//   A fp32 rows 128B/8 granules: g' = g ^ (row&7)    (same class as attn K reads, 0 confl)
//   B fp16 rows  64B/4 granules: g' = g ^ ((row>>1)&3) (round-5 measured 0 confl)
// sel 0:q (scaled 0.125*LOG2E) 1:k 2:v (TRANSPOSED out: vt[b,h,dk,s])
__global__ __launch_bounds__(256, 3) void qkv_gemm(
    const float* __restrict__ Qf, const float* __restrict__ Kf, const float* __restrict__ Vf,
    const _Float16* __restrict__ wh,
    const float* __restrict__ bq, const float* __restrict__ bk, const float* __restrict__ bv,
    _Float16* __restrict__ qo, _Float16* __restrict__ ko, _Float16* __restrict__ vt) {
  __shared__ __align__(16) float Af[2][128 * 32];      // 16KB x2
  __shared__ __align__(16) _Float16 Bs[2][128 * 32];   // 8KB x2
  const int tid = threadIdx.x;
  const int wave = tid >> 6, lane = tid & 63;
  const int m15 = lane & 15, quad = lane >> 4;
  const int m0 = blockIdx.x * 128;
  const int gn0 = blockIdx.y * 128;
  const int sel = gn0 >> 10;       // 0:q 1:k 2:v (128 | 1024, no straddle)
  const int n0 = gn0 & 1023;
  const float* Ag = (sel == 0) ? Qf : (sel == 1) ? Kf : Vf;
  const _Float16* Wg = wh + (size_t)sel * (DMODEL * DMODEL);
  const float* bias = (sel == 0) ? bq : (sel == 1) ? bk : bv;

  const int wm = (wave & 1) * 64, wn = (wave >> 1) * 64;

  // DMA source coords (pre-swizzled; LDS dest is linear chunk base + 16*lane)
  const int a_r = lane >> 3, a_g = (lane & 7) ^ ((lane >> 3) & 7);  // A: 8 granules/row
  const int b_r = lane >> 2, b_g = (lane & 3) ^ ((lane >> 3) & 3); // B: 4 granules/row

  // read-side swizzled granule byte offsets
  const int rgrA0 = (((2 * quad) ^ (m15 & 7)) << 4);
  const int rgrA1 = (((2 * quad + 1) ^ (m15 & 7)) << 4);
  const int rgrB = ((quad ^ ((m15 >> 1) & 3)) << 4);

  f32x4 acc[4][4];
#pragma unroll
  for (int i = 0; i < 4; i++)
#pragma unroll
    for (int j = 0; j < 4; j++) {
      f32x4 z = {0.f, 0.f, 0.f, 0.f};
      acc[i][j] = z;
    }

  auto issueTile = [&](int kk, int nb) {
#pragma unroll
    for (int p = 0; p < 4; p++) {  // A fp32 128x32: 4 issues (rows (p*4+wave)*8 ..+8)
      int row = (p * 4 + wave) * 8 + a_r;
      async_copy16(Ag + (size_t)(m0 + row) * DMODEL + kk + a_g * 4,
                   (char*)&Af[nb][0] + p * 4096 + wave * 1024);
    }
#pragma unroll
    for (int p = 0; p < 2; p++) {  // B fp16 128x32: 2 issues (rows (p*4+wave)*16 ..+16)
      int row = (p * 4 + wave) * 16 + b_r;
      async_copy16(Wg + (size_t)(n0 + row) * DMODEL + kk + b_g * 8,
                   (char*)&Bs[nb][0] + p * 4096 + wave * 1024);
    }
  };

  // prologue: 2 tiles in flight; wait only for tile 0 (6 of tile 1 stay outstanding)
  issueTile(0, 0);
  issueTile(32, 1);
  WAIT_VMCNT(6);
  RAW_BARRIER();

  for (int kt = 0; kt < 32; kt++) {
    const int buf = kt & 1;
    const char* ab = (const char*)&Af[buf][0];
    const char* bb = (const char*)&Bs[buf][0];
    half8 af[4], bf[4];
#pragma unroll
    for (int i = 0; i < 4; i++) {
      int row = wm + i * 16 + m15;
      f32x4 lo = *(const f32x4*)(ab + row * 128 + rgrA0);
      f32x4 hi = *(const f32x4*)(ab + row * 128 + rgrA1);
      half8 h;
      h[0] = (_Float16)lo[0]; h[1] = (_Float16)lo[1];
      h[2] = (_Float16)lo[2]; h[3] = (_Float16)lo[3];
      h[4] = (_Float16)hi[0]; h[5] = (_Float16)hi[1];
      h[6] = (_Float16)hi[2]; h[7] = (_Float16)hi[3];
      af[i] = h;
    }
#pragma unroll
    for (int j = 0; j < 4; j++)
      bf[j] = *(const half8*)(bb + (wn + j * 16 + m15) * 64 + rgrB);
#pragma unroll
    for (int i = 0; i < 4; i++)
#pragma unroll
      for (int j = 0; j < 4; j++)
        acc[i][j] = __builtin_amdgcn_mfma_f32_16x16x32_f16(af[i], bf[j], acc[i][j], 0, 0, 0);
    if (kt == 31) break;
    RAW_BARRIER();  // all waves done reading buf -> safe to overwrite
    if (kt < 30) {
      issueTile((kt + 2) * 32, buf);
      WAIT_VMCNT(6);  // my tile kt+1 landed (tile kt+2's 6 stay in flight)
    } else {
      WAIT_VMCNT(0);  // last tile (31) must be fully landed
    }
    RAW_BARRIER();  // everyone's tile kt+1 landed -> safe to read buf^1
  }
  // epilogue: C/D layout col=lane&15, row=quad*4+r
  if (sel != 2) {
    _Float16* outp = (sel == 0) ? qo : ko;
    const float scale = (sel == 0) ? (0.125f * LOG2E) : 1.0f;
#pragma unroll
    for (int i = 0; i < 4; i++) {
#pragma unroll
      for (int j = 0; j < 4; j++) {
        int gn = n0 + wn + j * 16 + m15;
        float bb = bias[gn];
#pragma unroll
        for (int r = 0; r < 4; r++) {
          int gm = m0 + wm + i * 16 + quad * 4 + r;
          outp[(size_t)gm * DMODEL + gn] = (_Float16)((acc[i][j][r] + bb) * scale);
        }
      }
    }
  } else {
    // V transposed store: vt[((b*16+h)*64+dk)*2048 + s], 4 consecutive s per thread (half4)
#pragma unroll
    for (int i = 0; i < 4; i++) {
      int gm0 = m0 + wm + i * 16 + quad * 4;  // rows r=0..3 contiguous
      int b = gm0 >> 11, s = gm0 & 2047;
#pragma unroll
      for (int j = 0; j < 4; j++) {
        int gn = n0 + wn + j * 16 + m15;
        int h = gn >> 6, dk = gn & 63;
        float bb = bias[gn];
        half4 hv;
        hv[0] = (_Float16)(acc[i][j][0] + bb);
        hv[1] = (_Float16)(acc[i][j][1] + bb);
        hv[2] = (_Float16)(acc[i][j][2] + bb);
        hv[3] = (_Float16)(acc[i][j][3] + bb);
        *(half4*)(vt + ((size_t)(b * 16 + h) * 64 + dk) * 2048 + s) = hv;
      }
    }
  }
}

// ---------------- flash attention v4: hybrid 2x2 wave split, all-b128 LDS, in-reg P ----------------
// (unchanged from round 4 -- verified, no longer the bottleneck)
__global__ __launch_bounds__(256) void attn_kernel(const _Float16* __restrict__ qh,
                                                   const _Float16* __restrict__ kh,
                                                   const _Float16* __restrict__ vt,
                                                   _Float16* __restrict__ ctx) {
  // [0,16K) Ks[2][64][64], [16K,32K) Vs[2][64][64]; epilogue reuses [0,17664) as Ored/Lred.
  __shared__ __align__(16) char smem[32768];
  const int tid = threadIdx.x;
  const int wave = tid >> 6, lane = tid & 63;
  const int m15 = lane & 15, qd = lane >> 4;
  const int wq = wave >> 1, ws = wave & 1;
  const int q0 = blockIdx.x * 64;
  const int h = blockIdx.y, b = blockIdx.z;
  const size_t base = (size_t)b * S_LEN * DMODEL + (size_t)h * DHEAD;  // q/k/ctx base
  const size_t vbase = (size_t)(b * 16 + h) * 64 * 2048;               // vt base

  // Q fragments (pre-scaled by 0.125*log2e): B-layout n=m15 (q row), k=qd*8+j (dk)
  half8 qf[2][2];
#pragma unroll
  for (int qt = 0; qt < 2; qt++) {
    const _Float16* qp = qh + base + (size_t)(q0 + wq * 32 + qt * 16 + m15) * DMODEL + qd * 8;
    qf[qt][0] = *(const half8*)qp;
    qf[qt][1] = *(const half8*)(qp + 32);
  }

  // staging: per-lane pre-swizzled global sources (16B granule: slot s8 holds logical s8^l8)
  const int l8 = lane >> 3, s8 = lane & 7;
  const int swz = (s8 ^ l8) * 8;  // halfs within a 64-half row
  const _Float16* ksrc = kh + base + (size_t)(wave * 8 + l8) * DMODEL + swz;
  const _Float16* vsrc = vt + vbase + (size_t)(wave * 8 + l8) * S_LEN + swz;
  char* kdst = smem + wave * 1024;
  char* vdst = smem + 16384 + wave * 1024;

  // read-side swizzled granule byte offsets (row&7 == m15&7 for all read rows)
  const int kgr = ((qd ^ (m15 & 7)) << 4);             // K: dk granule G=qd (dk 0..31)
  const int vgr = (((ws * 4 + qd) ^ (m15 & 7)) << 4);  // V: s' granule G=ws*4+qd
  const int krow = ws * 32 + m15;                      // + 16t

  f32x4 acc[4][2];  // [dk-tile][q-tile] partial O^T over this wave's 32-s' slice
#pragma unroll
  for (int i = 0; i < 4; i++)
#pragma unroll
    for (int j = 0; j < 2; j++) { f32x4 z = {0.f, 0.f, 0.f, 0.f}; acc[i][j] = z; }
  float ls[2] = {0.f, 0.f};  // per-lane partial row sums (q = qt*16+m15)

  // prologue: stage tile 0 into buf 0
#pragma unroll
  for (int p = 0; p < 2; p++) {
    async_copy16(ksrc + (size_t)(p * 32) * DMODEL, kdst + p * 4096);
    async_copy16(vsrc + (size_t)(p * 32) * S_LEN, vdst + p * 4096);
  }
  __syncthreads();

  for (int it = 0; it < 32; it++) {
    const int buf = it & 1;
    if (it < 31) {
      const int kv = (it + 1) * 64;
#pragma unroll
      for (int p = 0; p < 2; p++) {
        async_copy16(ksrc + (size_t)(kv + p * 32) * DMODEL, kdst + (buf ^ 1) * 8192 + p * 4096);
        async_copy16(vsrc + (size_t)(p * 32) * S_LEN + kv, vdst + (buf ^ 1) * 8192 + p * 4096);
      }
    }
    const char* kb = smem + buf * 8192;
    const char* vb = smem + 16384 + buf * 8192;

    // ---- K slice fragments: A-layout row = ws*32+16t+m15 (s'), k=qd*8+j (dk) ----
    half8 kf[2][2];
#pragma unroll
    for (int t = 0; t < 2; t++) {
      kf[t][0] = *(const half8*)(kb + (krow + 16 * t) * 128 + kgr);
      kf[t][1] = *(const half8*)(kb + (krow + 16 * t) * 128 + (kgr ^ 64));
    }

    // ---- QK^T: sc[t][qt] = P[s'_slice=16t+qd*4+r][q=qt*16+m15] ----
    f32x4 sc[2][2];
#pragma unroll
    for (int t = 0; t < 2; t++)
#pragma unroll
      for (int qt = 0; qt < 2; qt++) {
        f32x4 z = {0.f, 0.f, 0.f, 0.f};
        sc[t][qt] = __builtin_amdgcn_mfma_f32_16x16x32_f16(kf[t][0], qf[qt][0], z, 0, 0, 0);
        sc[t][qt] = __builtin_amdgcn_mfma_f32_16x16x32_f16(kf[t][1], qf[qt][1], sc[t][qt], 0, 0, 0);
      }

    // ---- p = exp2(score) (raw); lane-local row sums; pack pairs to half2 words ----
    int pk[2][2][2];
#pragma unroll
    for (int t = 0; t < 2; t++)
#pragma unroll
      for (int qt = 0; qt < 2; qt++) {
        float e0 = __builtin_amdgcn_exp2f(sc[t][qt][0]);
        float e1 = __builtin_amdgcn_exp2f(sc[t][qt][1]);
        float e2 = __builtin_amdgcn_exp2f(sc[t][qt][2]);
        float e3 = __builtin_amdgcn_exp2f(sc[t][qt][3]);
        ls[qt] += (e0 + e1) + (e2 + e3);
        pk[t][qt][0] = __builtin_bit_cast(int, __builtin_amdgcn_cvt_pkrtz(e0, e1));
        pk[t][qt][1] = __builtin_bit_cast(int, __builtin_amdgcn_cvt_pkrtz(e2, e3));
      }

    // ---- butterfly (validated r2): tiles (0,1) -> lane holds P[s'_slice=qd*8+jj][q],
    // exactly the PV B-fragment (k=qd*8+jj) for the wave's 32-s' slice.
    half8 pA[2];
#pragma unroll
    for (int qt = 0; qt < 2; qt++) {
      i32x4 fh;
#pragma unroll
      for (int p = 0; p < 2; p++) {
        auto s1 = __builtin_amdgcn_permlane32_swap(pk[0][qt][p], pk[1][qt][p], false, false);
        auto s2 = __builtin_amdgcn_permlane16_swap(s1[0], s1[1], false, false);
        fh[p] = (int)s2[0];      // jj 0..3 slot
        fh[2 + p] = (int)s2[1];  // jj 4..7 slot
      }
      pA[qt] = __builtin_bit_cast(half8, fh);
    }

    // ---- PV: acc[td][qt] += V^T[dk=td*16+m15][s' slice] x P (K=32, one b128 per td) ----
#pragma unroll
    for (int td = 0; td < 4; td++) {
      half8 vf = *(const half8*)(vb + (td * 16 + m15) * 128 + vgr);
#pragma unroll
      for (int qt = 0; qt < 2; qt++)
        acc[td][qt] = __builtin_amdgcn_mfma_f32_16x16x32_f16(vf, pA[qt], acc[td][qt], 0, 0, 0);
    }
    __syncthreads();  // drains this wave's DMA (vmcnt 0) + all waves done reading buf
  }

  // ---- cross-ws reduction through LDS (K/V buffers dead after final barrier) ----
  float* Ored = (float*)smem;            // [64 q][68] f32 (stride 68: uniform bank spread)
  float* Lred = (float*)(smem + 17408);  // [64 q] f32 (ws=1 partials)

#pragma unroll
  for (int qt = 0; qt < 2; qt++) {  // reduce over quads (disjoint s' per qd)
    ls[qt] += __shfl_xor(ls[qt], 16);
    ls[qt] += __shfl_xor(ls[qt], 32);
  }

  if (ws == 1) {
#pragma unroll
    for (int qt = 0; qt < 2; qt++) {
      int q = wq * 32 + qt * 16 + m15;
      if (qd == 0) Lred[q] = ls[qt];
#pragma unroll
      for (int td = 0; td < 4; td++)
        *(f32x4*)&Ored[q * 68 + td * 16 + qd * 4] = acc[td][qt];
    }
  }
  __syncthreads();

  if (ws == 0) {
#pragma unroll
    for (int qt = 0; qt < 2; qt++) {
      int q = wq * 32 + qt * 16 + m15;
      const float inv = 1.0f / (ls[qt] + Lred[q]);
#pragma unroll
      for (int td = 0; td < 4; td++) {
        f32x4 o = acc[td][qt] + *(const f32x4*)&Ored[q * 68 + td * 16 + qd * 4];
        half4 hv;
#pragma unroll
        for (int r = 0; r < 4; r++) hv[r] = (_Float16)(o[r] * inv);
        *(half4*)(ctx + base + (size_t)(q0 + q) * DMODEL + td * 16 + qd * 4) = hv;
      }
    }
  }
}

// ---------------- output projection v3: counted-vmcnt pipeline, BM=64 ----------------
__global__ __launch_bounds__(256, 4) void out_gemm(const _Float16* __restrict__ ch,
                                                   const _Float16* __restrict__ who,
                                                   const float* __restrict__ bo,
                                                   float* __restrict__ out) {
  __shared__ __align__(16) _Float16 As[2][64 * 32];    // 4KB x2
  __shared__ __align__(16) _Float16 Bs[2][128 * 32];   // 8KB x2
  const int tid = threadIdx.x;
  const int wave = tid >> 6, lane = tid & 63;
  const int m15 = lane & 15, quad = lane >> 4;
  const int m0 = blockIdx.x * 64, n0 = blockIdx.y * 128;
  const int wm = (wave & 1) * 32, wn = (wave >> 1) * 64;
  const int b_r = lane >> 2, b_g = (lane & 3) ^ ((lane >> 3) & 3);
  const int rgr = ((quad ^ ((m15 >> 1) & 3)) << 4);

  f32x4 acc[2][4];
#pragma unroll
  for (int i = 0; i < 2; i++)
#pragma unroll
    for (int j = 0; j < 4; j++) {
      f32x4 z = {0.f, 0.f, 0.f, 0.f};
      acc[i][j] = z;
    }

  auto issueTile = [&](int kk, int nb) {
    {  // A 64x32 fp16: 1 issue (rows wave*16 ..+16)
      int row = wave * 16 + b_r;
      async_copy16(ch + (size_t)(m0 + row) * DMODEL + kk + b_g * 8,
                   (char*)&As[nb][0] + wave * 1024);
    }
#pragma unroll
    for (int p = 0; p < 2; p++) {  // B 128x32 fp16: 2 issues
      int row = (p * 4 + wave) * 16 + b_r;
      async_copy16(who + (size_t)(n0 + row) * DMODEL + kk + b_g * 8,
                   (char*)&Bs[nb][0] + p * 4096 + wave * 1024);
    }
  };

  issueTile(0, 0);
  issueTile(32, 1);
  WAIT_VMCNT(3);
  RAW_BARRIER();

  for (int kt = 0; kt < 32; kt++) {
    const int buf = kt & 1;
    half8 af[2], bf[4];
#pragma unroll
    for (int i = 0; i < 2; i++)
      af[i] = *(const half8*)((char*)&As[buf][0] + (wm + i * 16 + m15) * 64 + rgr);
#pragma unroll
    for (int j = 0; j < 4; j++)
      bf[j] = *(const half8*)((char*)&Bs[buf][0] + (wn + j * 16 + m15) * 64 + rgr);
#pragma unroll
    for (int i = 0; i < 2; i++)
#pragma unroll
      for (int j = 0; j < 4; j++)
        acc[i][j] = __builtin_amdgcn_mfma_f32_16x16x32_f16(af[i], bf[j], acc[i][j], 0, 0, 0);
    if (kt == 31) break;
    RAW_BARRIER();
    if (kt < 30) {
      issueTile((kt + 2) * 32, buf);
      WAIT_VMCNT(3);
    } else {
      WAIT_VMCNT(0);
    }
    RAW_BARRIER();
  }
#pragma unroll
  for (int i = 0; i < 2; i++) {
#pragma unroll
    for (int j = 0; j < 4; j++) {
      int gn = n0 + wn + j * 16 + m15;
      float bb = bo[gn];
#pragma unroll
      for (int r = 0; r < 4; r++) {
        int gm = m0 + wm + i * 16 + quad * 4 + r;
        out[(size_t)gm * DMODEL + gn] = acc[i][j][r] + bb;
      }
    }
  }
}

extern "C" void kernel_launch(void* const* d_in, const int* in_sizes, int n_in,
                              void* d_out, int out_size, void* d_ws, size_t ws_size,
                              hipStream_t stream) {
  (void)in_sizes; (void)n_in; (void)out_size; (void)ws_size;
  const float* Q  = (const float*)d_in[0];
  const float* K  = (const float*)d_in[1];
  const float* V  = (const float*)d_in[2];
  const float* wq = (const float*)d_in[3];
  const float* bq = (const float*)d_in[4];
  const float* wk = (const float*)d_in[5];
  const float* bk = (const float*)d_in[6];
  const float* wv = (const float*)d_in[7];
  const float* bv = (const float*)d_in[8];
  const float* wo = (const float*)d_in[9];
  const float* bo = (const float*)d_in[10];
  float* out = (float*)d_out;

  // Scratch plan (16 MB d_ws + d_out reuse), timeline:
  //   qh, kh (fp16, 8 MB each)  -> inside d_out (dead before out_gemm writes fp32 there)
  //   vt (fp16 transposed, 8MB) -> ws[0:8M)   -- alive qkv..attn
  //   wh (fp16 wq|wk|wv, 6 MB)  -> ws[8M:14M) -- alive only during qkv_gemm
  //   ch (fp16 ctx, 8 MB)       -> ws[8M:16M) -- written by attn (overlays wh, disjoint in time)
  //   who (fp16 wo, 2 MB)       -> ws[0:2M)   -- written AFTER attn (overlays dead vt)
  _Float16* qh = (_Float16*)d_out;
  _Float16* kh = qh + (size_t)4194304;
  _Float16* vt = (_Float16*)d_ws;
  _Float16* wh = vt + (size_t)4194304;
  _Float16* ch = vt + (size_t)4194304;
  _Float16* who = (_Float16*)d_ws;

  convert_w<<<dim3(1024, 3), 256, 0, stream>>>(wq, wk, wv, wh);
  qkv_gemm<<<dim3(32, 24), 256, 0, stream>>>(Q, K, V, wh, bq, bk, bv, qh, kh, vt);
  attn_kernel<<<dim3(32, 16, 2), 256, 0, stream>>>(qh, kh, vt, ch);
  convert_wo<<<dim3(1024), 256, 0, stream>>>(wo, who);
  out_gemm<<<dim3(64, 8), 256, 0, stream>>>(ch, who, bo, out);
}